// Round 2
// baseline (242.726 us; speedup 1.0000x reference)
//
#include <hip/hip_runtime.h>
#include <hip/hip_bf16.h>

#define B_ 8
#define E_ 2048
#define N_ 2048
#define F_ 128

#define BM 32      // hyperedge rows per block
#define BK 64      // K chunk
#define AP 72      // A tile LDS pitch (bf16 elems), padded
#define BP 72      // B tile LDS pitch
#define WP 136     // W LDS pitch
#define MP 136     // msg LDS pitch

using bf16x8 = __bf16 __attribute__((ext_vector_type(8)));
using fx4    = float __attribute__((ext_vector_type(4)));

// ---------------- prep: node [B][N][F] f32 -> nodeT [B][F][N] bf16 ----------------
__global__ __launch_bounds__(256) void prep_node(const float* __restrict__ node,
                                                 __bf16* __restrict__ nodeT) {
    __shared__ __align__(16) __bf16 tile[F_][72];   // [f][n], 64 n + pad
    const int bid = blockIdx.x;
    const int b  = bid >> 5;            // 0..7
    const int n0 = (bid & 31) * 64;     // n tile base
    const int t  = threadIdx.x;

#pragma unroll
    for (int p = 0; p < 8; ++p) {
        int idx = t + 256 * p;          // 0..2047
        int n   = idx >> 5;             // 0..63
        int f4  = (idx & 31) * 4;
        float4 v = *(const float4*)&node[((size_t)b * N_ + n0 + n) * F_ + f4];
        tile[f4 + 0][n] = (__bf16)v.x;
        tile[f4 + 1][n] = (__bf16)v.y;
        tile[f4 + 2][n] = (__bf16)v.z;
        tile[f4 + 3][n] = (__bf16)v.w;
    }
    __syncthreads();
#pragma unroll
    for (int p = 0; p < 4; ++p) {
        int idx = t + 256 * p;          // 0..1023
        int f   = idx >> 3;             // 0..127
        int n8  = (idx & 7) * 8;
        uint4 v = *(const uint4*)&tile[f][n8];
        *(uint4*)&nodeT[((size_t)b * F_ + f) * N_ + n0 + n8] = v;
    }
}

// ---------------- prep: W f32 -> bf16 ----------------
__global__ __launch_bounds__(256) void prep_w(const float* __restrict__ W,
                                              __bf16* __restrict__ Wb) {
    int idx = blockIdx.x * 256 + threadIdx.x;   // 0..4095
    float4 v = *(const float4*)&W[idx * 4];
    __bf16 o[4] = {(__bf16)v.x, (__bf16)v.y, (__bf16)v.z, (__bf16)v.w};
    *(uint2*)&Wb[idx * 4] = *(const uint2*)o;
}

// ---------------- main fused kernel ----------------
__global__ __launch_bounds__(256) void v2h_main(const float* __restrict__ adj,
                                                const __bf16* __restrict__ nodeT,
                                                const __bf16* __restrict__ Wb,
                                                const float* __restrict__ bias,
                                                float* __restrict__ out) {
    // A/B staging region, reused as msg buffer in the epilogue
    __shared__ __align__(16) __bf16 smemAB[BM * AP + F_ * BP];   // 11520 elems
    __shared__ __align__(16) __bf16 Ws[F_ * WP];                 // 17408 elems
    __shared__ float normS[BM];

    __bf16* As = smemAB;                 // [BM][AP]
    __bf16* Bs = smemAB + BM * AP;       // [F_][BP]  (f-major, k-contiguous)
    __bf16* Ms = smemAB;                 // [BM][MP]  (epilogue reuse)

    const int t    = threadIdx.x;
    const int bid  = blockIdx.x;
    const int b    = bid & 7;            // batch -> XCD locality for nodeT
    const int e0   = (bid >> 3) * BM;
    const int w    = t >> 6;
    const int lane = t & 63;
    const int wm   = w & 1;              // row group (16 rows)
    const int wf   = w >> 1;             // f group (64 cols)
    const int l15  = lane & 15;
    const int quad = lane >> 4;

    // stage W (128x128 bf16) into LDS: 128 rows x 16 uint4-chunks = 2048 chunks
#pragma unroll
    for (int p = 0; p < 8; ++p) {
        int idx = t + 256 * p;           // 0..2047
        int g   = idx >> 4;              // 0..127
        int f8  = (idx & 15) * 8;        // 0..120
        *(uint4*)&Ws[g * WP + f8] = *(const uint4*)&Wb[g * F_ + f8];
    }

    fx4 acc[4] = {};                     // 4 f-tiles of 16x16 accum
    float cnt0 = 0.f, cnt1 = 0.f;        // per-thread partial -1 counts

    const int ar0 = t >> 4;              // A row (pass 0): 0..15
    const int ac  = (t & 15) * 4;        // A col base
    const float*  adjR0 = adj + ((size_t)b * E_ + e0 + ar0) * N_;
    const float*  adjR1 = adjR0 + (size_t)16 * N_;
    const __bf16* nTB   = nodeT + (size_t)b * F_ * N_;

    for (int k0 = 0; k0 < N_; k0 += BK) {
        // global loads into registers (overlap previous iteration's LDS reads)
        float4 a0 = *(const float4*)(adjR0 + k0 + ac);
        float4 a1 = *(const float4*)(adjR1 + k0 + ac);
        uint4 bv[4];
#pragma unroll
        for (int p = 0; p < 4; ++p) {
            int idx = t + 256 * p;       // 0..1023
            int f   = idx >> 3;          // 0..127
            int k8  = (idx & 7) * 8;     // 0..56 (BK=64 -> 8 chunks/row)
            bv[p] = *(const uint4*)&nTB[(size_t)f * N_ + k0 + k8];
        }

        __syncthreads();   // previous iteration's LDS reads complete

        // mask convert + store A, accumulate norm counts
        {
            float m0 = (a0.x == -1.f) ? 1.f : 0.f;
            float m1 = (a0.y == -1.f) ? 1.f : 0.f;
            float m2 = (a0.z == -1.f) ? 1.f : 0.f;
            float m3 = (a0.w == -1.f) ? 1.f : 0.f;
            cnt0 += m0 + m1 + m2 + m3;
            __bf16 pk[4] = {(__bf16)m0, (__bf16)m1, (__bf16)m2, (__bf16)m3};
            *(uint2*)&As[ar0 * AP + ac] = *(const uint2*)pk;
        }
        {
            float m0 = (a1.x == -1.f) ? 1.f : 0.f;
            float m1 = (a1.y == -1.f) ? 1.f : 0.f;
            float m2 = (a1.z == -1.f) ? 1.f : 0.f;
            float m3 = (a1.w == -1.f) ? 1.f : 0.f;
            cnt1 += m0 + m1 + m2 + m3;
            __bf16 pk[4] = {(__bf16)m0, (__bf16)m1, (__bf16)m2, (__bf16)m3};
            *(uint2*)&As[(ar0 + 16) * AP + ac] = *(const uint2*)pk;
        }
        // store B tile (already bf16, k-contiguous)
#pragma unroll
        for (int p = 0; p < 4; ++p) {
            int idx = t + 256 * p;
            int f   = idx >> 3;
            int k8  = (idx & 7) * 8;
            *(uint4*)&Bs[f * BP + k8] = bv[p];
        }

        __syncthreads();   // tiles visible

        // MFMA: A[m=lane&15][k=quad*8+j], B[k=quad*8+j][n=lane&15]
#pragma unroll
        for (int ks = 0; ks < 2; ++ks) {
            bf16x8 af = *(const bf16x8*)&As[(16 * wm + l15) * AP + ks * 32 + quad * 8];
#pragma unroll
            for (int ft = 0; ft < 4; ++ft) {
                bf16x8 bf = *(const bf16x8*)&Bs[(wf * 64 + ft * 16 + l15) * BP + ks * 32 + quad * 8];
                acc[ft] = __builtin_amdgcn_mfma_f32_16x16x32_bf16(af, bf, acc[ft], 0, 0, 0);
            }
        }
    }

    // ---- norm reduction: 16 threads (t&15) share each row ----
#pragma unroll
    for (int m = 1; m < 16; m <<= 1) {
        cnt0 += __shfl_xor(cnt0, m, 16);
        cnt1 += __shfl_xor(cnt1, m, 16);
    }
    if ((t & 15) == 0) {
        normS[ar0]      = fmaxf(cnt0, 1.f);
        normS[ar0 + 16] = fmaxf(cnt1, 1.f);
    }
    __syncthreads();   // normS ready; all K-loop LDS reads done -> Ms reuse safe

    // ---- scale by 1/norm, write msg (bf16) to LDS in [m][f] layout ----
    const int rbase = 16 * wm + quad * 4;
    float rn[4];
#pragma unroll
    for (int r = 0; r < 4; ++r) rn[r] = 1.f / normS[rbase + r];
#pragma unroll
    for (int ft = 0; ft < 4; ++ft) {
        int fcol = wf * 64 + ft * 16 + l15;
#pragma unroll
        for (int r = 0; r < 4; ++r)
            Ms[(rbase + r) * MP + fcol] = (__bf16)(acc[ft][r] * rn[r]);
    }
    __syncthreads();

    // ---- second GEMM: out[m][g] = sum_f msg[m][f] * W[g][f] ----
    fx4 acc2[4] = {};
#pragma unroll
    for (int ks = 0; ks < 4; ++ks) {
        bf16x8 af = *(const bf16x8*)&Ms[(16 * wm + l15) * MP + ks * 32 + quad * 8];
#pragma unroll
        for (int gt = 0; gt < 4; ++gt) {
            bf16x8 wfr = *(const bf16x8*)&Ws[(wf * 64 + gt * 16 + l15) * WP + ks * 32 + quad * 8];
            acc2[gt] = __builtin_amdgcn_mfma_f32_16x16x32_bf16(af, wfr, acc2[gt], 0, 0, 0);
        }
    }

    // ---- bias + relu + store ----
#pragma unroll
    for (int gt = 0; gt < 4; ++gt) {
        int g = wf * 64 + gt * 16 + l15;
        float bb = bias[g];
#pragma unroll
        for (int r = 0; r < 4; ++r) {
            int e = e0 + rbase + r;
            float v = acc2[gt][r] + bb;
            out[((size_t)b * E_ + e) * F_ + g] = fmaxf(v, 0.f);
        }
    }
}

extern "C" void kernel_launch(void* const* d_in, const int* in_sizes, int n_in,
                              void* d_out, int out_size, void* d_ws, size_t ws_size,
                              hipStream_t stream) {
    const float* node = (const float*)d_in[0];   // [B,N,F]
    const float* adj  = (const float*)d_in[1];   // [B,E,N]
    const float* W    = (const float*)d_in[2];   // [F,F]
    const float* bias = (const float*)d_in[3];   // [F]
    float* out = (float*)d_out;                  // [B,E,F]

    __bf16* nodeT = (__bf16*)d_ws;                                   // 4 MB
    __bf16* Wb    = (__bf16*)((char*)d_ws + (size_t)B_ * F_ * N_ * 2);

    prep_node<<<256, 256, 0, stream>>>(node, nodeT);
    prep_w<<<16, 256, 0, stream>>>(W, Wb);
    v2h_main<<<512, 256, 0, stream>>>(adj, nodeT, Wb, bias, out);
}